// Round 10
// baseline (331.383 us; speedup 1.0000x reference)
//
#include <hip/hip_runtime.h>
#include <hip/hip_fp16.h>

#define N_NODES 50000
#define NFEAT   256
#define NGRAPH  64
#define NEDGE   800000
#define NBLK_SCAN 196  // ceil(50000/256)

typedef __attribute__((ext_vector_type(8))) _Float16 half8;
typedef __attribute__((ext_vector_type(2))) _Float16 h2v;
typedef __attribute__((ext_vector_type(4))) float f32x4;

static __device__ __forceinline__ float h2f(unsigned short u) {
    return __half2float(__ushort_as_half(u));
}
static __device__ __forceinline__ unsigned short f2h(float f) {
    return __half_as_ushort(__float2half(f));
}

// ================= CSR build =================
__global__ void k_count(const int* __restrict__ dst, int* __restrict__ cnt) {
    int e = blockIdx.x * 256 + threadIdx.x;
    if (e < NEDGE) atomicAdd(&cnt[dst[e]], 1);
}

__global__ __launch_bounds__(256) void k_scan1(const int* __restrict__ cnt,
                                               int* __restrict__ row_start,
                                               int* __restrict__ bsum) {
    const int t = threadIdx.x, i = blockIdx.x * 256 + t;
    const int lane = t & 63, w = t >> 6;
    const int c = (i < N_NODES) ? cnt[i] : 0;
    int incl = c;
#pragma unroll
    for (int off = 1; off < 64; off <<= 1) {
        int u = __shfl_up(incl, off, 64);
        if (lane >= off) incl += u;
    }
    __shared__ int wtot[4];
    if (lane == 63) wtot[w] = incl;
    __syncthreads();
    int wbase = 0;
#pragma unroll
    for (int k = 0; k < 4; ++k) wbase += (k < w) ? wtot[k] : 0;
    if (i < N_NODES) row_start[i] = wbase + incl - c;
    if (t == 255) bsum[blockIdx.x] = wbase + incl;
}

__global__ __launch_bounds__(256) void k_scan2(int* __restrict__ bsum) {
    const int t = threadIdx.x, lane = t & 63, w = t >> 6;
    const int c = (t < NBLK_SCAN) ? bsum[t] : 0;
    int incl = c;
#pragma unroll
    for (int off = 1; off < 64; off <<= 1) {
        int u = __shfl_up(incl, off, 64);
        if (lane >= off) incl += u;
    }
    __shared__ int wtot[4];
    if (lane == 63) wtot[w] = incl;
    __syncthreads();
    int wbase = 0;
#pragma unroll
    for (int k = 0; k < 4; ++k) wbase += (k < w) ? wtot[k] : 0;
    if (t < NBLK_SCAN) bsum[t] = wbase + incl - c;
}

__global__ void k_scan3(int* __restrict__ row_start, const int* __restrict__ bsum,
                        int* __restrict__ cnt_cursor, float* __restrict__ dinv) {
    const int i = blockIdx.x * 256 + threadIdx.x;
    if (i >= N_NODES) return;
    const int c = cnt_cursor[i];
    const int start = row_start[i] + bsum[blockIdx.x];
    row_start[i] = start;
    cnt_cursor[i] = start;
    dinv[i] = rsqrtf((float)c + 1.0f);
    if (i == 0) row_start[N_NODES] = NEDGE;
}

__global__ void k_place(const int* __restrict__ src, const int* __restrict__ dst,
                        int* __restrict__ cursor, const float* __restrict__ dinv,
                        unsigned int* __restrict__ csr) {
    int e = blockIdx.x * 256 + threadIdx.x;
    if (e < NEDGE) {
        int s = src[e], d = dst[e];
        float norm = dinv[s] * dinv[d];
        int pos = atomicAdd(&cursor[d], 1);
        csr[pos] = ((unsigned int)f2h(norm) << 16) | (unsigned int)s;
    }
}

// ================= W prep: W[k][n] f32 -> Wt [n][k] fp16 =================
__global__ void k_prep_w(const float* __restrict__ W1, const float* __restrict__ W2,
                         unsigned short* __restrict__ w1t, unsigned short* __restrict__ w2t) {
    const int l = blockIdx.x >> 8;
    const int idx = (blockIdx.x & 255) * 256 + threadIdx.x;
    const int n = idx >> 8, k = idx & 255;
    const float* W = l ? W2 : W1;
    unsigned short* wt = l ? w2t : w1t;
    wt[n * 256 + k] = f2h(W[k * 256 + n]);
}

// ================= fp16 MFMA GEMM: C[half][node][128] = A[M,256] @ W =================
// BM=32, BN=128: grid (1563, 2) = 3126 blocks (~12/CU) for latency hiding.
// Wave (wr,wc): rows [m0+wr*16,+16) x cols [wc*64,+64). B in 16KB dbuf swizzled LDS.
template <bool AF32>
__global__ __launch_bounds__(256) void k_gemm_mfma(const float* __restrict__ Af,
                                                   const unsigned short* __restrict__ Ah,
                                                   const unsigned short* __restrict__ Wt,
                                                   unsigned short* __restrict__ Ch, int M) {
    __shared__ unsigned short lds[2][4096];  // [buf][128 rows x 32 k], swizzled k-groups
    const int t = threadIdx.x;
    const int m0 = blockIdx.x * 32;
    const int half = blockIdx.y;
    const int w = t >> 6, lane = t & 63;
    const int wr = w >> 1, wc = w & 1;
    const int lr = lane & 15, g = lane >> 4;

    // staging: thread t covers B row sn (0..127), k-half sseg (16 k each)
    const int sn = t & 127, sseg = t >> 7;
    const int swz = (sn >> 1) & 3;
    const int kg0 = ((sseg * 2 + 0) ^ swz) * 8;
    const int kg1 = ((sseg * 2 + 1) ^ swz) * 8;
    const unsigned short* wrow = Wt + (size_t)(half * 128 + sn) * 256 + sseg * 16;

    f32x4 acc[4] = {};
    half8 s0, s1;          // staged B regs for next K-step
    half8 a_cur, a_nxt;

#define LOADB(KS)                                  \
    {                                              \
        const unsigned short* p = wrow + (KS)*32;  \
        s0 = *(const half8*)p;                     \
        s1 = *(const half8*)(p + 8);               \
    }
#define WRITEB(BUF)                                \
    {                                              \
        unsigned short* b = &lds[BUF][sn * 32];    \
        *(half8*)(b + kg0) = s0;                   \
        *(half8*)(b + kg1) = s1;                   \
    }
#define LOADA(KS, DST)                                                               \
    {                                                                                \
        const int row = min(m0 + wr * 16 + lr, M - 1);                               \
        if (AF32) {                                                                  \
            const float* ap = Af + (size_t)row * 256 + (KS)*32 + g * 8;              \
            const float4 p0 = *(const float4*)ap;                                    \
            const float4 p1 = *(const float4*)(ap + 4);                              \
            half8 h;                                                                 \
            h[0] = (_Float16)p0.x; h[1] = (_Float16)p0.y;                            \
            h[2] = (_Float16)p0.z; h[3] = (_Float16)p0.w;                            \
            h[4] = (_Float16)p1.x; h[5] = (_Float16)p1.y;                            \
            h[6] = (_Float16)p1.z; h[7] = (_Float16)p1.w;                            \
            DST = h;                                                                 \
        } else {                                                                     \
            const unsigned short* ap = Ah + (size_t)((KS) >> 2) * N_NODES * 128 +    \
                                       (size_t)row * 128 + ((KS)&3) * 32 + g * 8;    \
            DST = *(const half8*)ap;                                                 \
        }                                                                            \
    }

    // prologue
    LOADB(0)
    WRITEB(0)
    LOADB(1)
    LOADA(0, a_cur)

    for (int ks = 0; ks < 8; ++ks) {
        __syncthreads();
        const int buf = ks & 1;
        if (ks < 7) WRITEB(buf ^ 1)
        if (ks < 6) LOADB(ks + 2)
        if (ks < 7) LOADA(ks + 1, a_nxt)

        half8 bf[4];
#pragma unroll
        for (int ni = 0; ni < 4; ++ni) {
            const int n = wc * 64 + ni * 16 + lr;
            bf[ni] = *(const half8*)(&lds[buf][n * 32 + ((g ^ ((n >> 1) & 3)) << 3)]);
        }

#pragma unroll
        for (int ni = 0; ni < 4; ++ni)
            acc[ni] = __builtin_amdgcn_mfma_f32_16x16x32_f16(a_cur, bf[ni], acc[ni], 0, 0, 0);
        a_cur = a_nxt;
    }
#undef LOADB
#undef WRITEB
#undef LOADA

    // write fp16 into [half][node][128]
    unsigned short* Chh = Ch + (size_t)half * N_NODES * 128;
    const int r0 = m0 + wr * 16 + g * 4;
#pragma unroll
    for (int ni = 0; ni < 4; ++ni) {
        const int c = wc * 64 + ni * 16 + lr;  // col within 128-plane
#pragma unroll
        for (int r = 0; r < 4; ++r) {
            if (r0 + r < M) Chh[(size_t)(r0 + r) * 128 + c] = f2h(acc[ni][r]);
        }
    }
}

// ================= aggregation: wave per (node, half); 16 lanes/edge; fdot2 ===========
__global__ __launch_bounds__(256) void k_aggregate(const unsigned short* __restrict__ h16,
                                                   const int* __restrict__ row_start,
                                                   const unsigned int* __restrict__ csr,
                                                   const float* __restrict__ dinv,
                                                   const float* __restrict__ bias,
                                                   unsigned short* __restrict__ out) {
    const int wid = blockIdx.x * 4 + (threadIdx.x >> 6);
    if (wid >= 2 * N_NODES) return;
    const int half = (wid >= N_NODES) ? 1 : 0;  // all half-0 wids first
    const int node = wid - half * N_NODES;
    const int lane = threadIdx.x & 63;
    const int sub = lane >> 4;   // 0..3: edge-pair index
    const int fl = lane & 15;    // 8 feats per lane
    const unsigned int* hu = (const unsigned int*)(h16 + (size_t)half * N_NODES * 128);

    float acc[8] = {};
    const int s0 = row_start[node], s1 = row_start[node + 1];
    const unsigned int* row = csr + s0;
    const int n = s1 - s0;

#define EDGEPAIR(EA, EB)                                                              \
    {                                                                                 \
        const unsigned int wnp = __builtin_amdgcn_perm(EB, EA, 0x07060302u);          \
        const h2v wn2 = __builtin_bit_cast(h2v, wnp);                                 \
        const uint4 va = *(const uint4*)(hu + (size_t)((EA)&0xffffu) * 64 + fl * 4);  \
        const uint4 vb = *(const uint4*)(hu + (size_t)((EB)&0xffffu) * 64 + fl * 4);  \
        unsigned int plo, phi;                                                        \
        plo = __builtin_amdgcn_perm(vb.x, va.x, 0x05040100u);                         \
        phi = __builtin_amdgcn_perm(vb.x, va.x, 0x07060302u);                         \
        acc[0] = __builtin_amdgcn_fdot2(__builtin_bit_cast(h2v, plo), wn2, acc[0], false); \
        acc[1] = __builtin_amdgcn_fdot2(__builtin_bit_cast(h2v, phi), wn2, acc[1], false); \
        plo = __builtin_amdgcn_perm(vb.y, va.y, 0x05040100u);                         \
        phi = __builtin_amdgcn_perm(vb.y, va.y, 0x07060302u);                         \
        acc[2] = __builtin_amdgcn_fdot2(__builtin_bit_cast(h2v, plo), wn2, acc[2], false); \
        acc[3] = __builtin_amdgcn_fdot2(__builtin_bit_cast(h2v, phi), wn2, acc[3], false); \
        plo = __builtin_amdgcn_perm(vb.z, va.z, 0x05040100u);                         \
        phi = __builtin_amdgcn_perm(vb.z, va.z, 0x07060302u);                         \
        acc[4] = __builtin_amdgcn_fdot2(__builtin_bit_cast(h2v, plo), wn2, acc[4], false); \
        acc[5] = __builtin_amdgcn_fdot2(__builtin_bit_cast(h2v, phi), wn2, acc[5], false); \
        plo = __builtin_amdgcn_perm(vb.w, va.w, 0x05040100u);                         \
        phi = __builtin_amdgcn_perm(vb.w, va.w, 0x07060302u);                         \
        acc[6] = __builtin_amdgcn_fdot2(__builtin_bit_cast(h2v, plo), wn2, acc[6], false); \
        acc[7] = __builtin_amdgcn_fdot2(__builtin_bit_cast(h2v, phi), wn2, acc[7], false); \
    }

    const int nfull = n & ~7;
    int j = 0;
    for (; j < nfull; j += 8) {
        const unsigned int ea = row[j + sub * 2];
        const unsigned int eb = row[j + sub * 2 + 1];
        EDGEPAIR(ea, eb)
    }
    if (j < n) {  // guarded tail (invalid slots: e=0 -> wn=0 -> contributes 0)
        const int ia = j + sub * 2, ib = ia + 1;
        const unsigned int ea = (ia < n) ? row[ia] : 0u;
        const unsigned int eb = (ib < n) ? row[ib] : 0u;
        EDGEPAIR(ea, eb)
    }
#undef EDGEPAIR

#pragma unroll
    for (int i = 0; i < 8; ++i) {
        acc[i] += __shfl_xor(acc[i], 16, 64);
        acc[i] += __shfl_xor(acc[i], 32, 64);
    }

    if (sub == 0) {  // lanes 0-15 hold the final sums
        const float dd = dinv[node];
        const float ws = dd * dd;
        const uint4 sh = *(const uint4*)(hu + (size_t)node * 64 + fl * 4);
        const float4 b0 = *(const float4*)(bias + half * 128 + fl * 8);
        const float4 b1 = *(const float4*)(bias + half * 128 + fl * 8 + 4);
        float r[8];
        r[0] = fmaf(h2f((unsigned short)(sh.x & 0xffff)), ws, acc[0]) + b0.x;
        r[1] = fmaf(h2f((unsigned short)(sh.x >> 16)),    ws, acc[1]) + b0.y;
        r[2] = fmaf(h2f((unsigned short)(sh.y & 0xffff)), ws, acc[2]) + b0.z;
        r[3] = fmaf(h2f((unsigned short)(sh.y >> 16)),    ws, acc[3]) + b0.w;
        r[4] = fmaf(h2f((unsigned short)(sh.z & 0xffff)), ws, acc[4]) + b1.x;
        r[5] = fmaf(h2f((unsigned short)(sh.z >> 16)),    ws, acc[5]) + b1.y;
        r[6] = fmaf(h2f((unsigned short)(sh.w & 0xffff)), ws, acc[6]) + b1.z;
        r[7] = fmaf(h2f((unsigned short)(sh.w >> 16)),    ws, acc[7]) + b1.w;
#pragma unroll
        for (int i = 0; i < 8; ++i) r[i] = fmaxf(r[i], 0.f);
        uint4 o;
        o.x = (unsigned int)f2h(r[0]) | ((unsigned int)f2h(r[1]) << 16);
        o.y = (unsigned int)f2h(r[2]) | ((unsigned int)f2h(r[3]) << 16);
        o.z = (unsigned int)f2h(r[4]) | ((unsigned int)f2h(r[5]) << 16);
        o.w = (unsigned int)f2h(r[6]) | ((unsigned int)f2h(r[7]) << 16);
        *(uint4*)((unsigned int*)(out + (size_t)half * N_NODES * 128) +
                  (size_t)node * 64 + fl * 4) = o;
    }
}

// ================= pooling (batch sorted) + head =================
__global__ void k_pool(const unsigned short* __restrict__ h2, const int* __restrict__ batch,
                       float* __restrict__ pooled) {
    const int strip = blockIdx.x * 2 + (threadIdx.x >> 7);
    const int tf = threadIdx.x & 127;
    const int f = tf * 2;
    const unsigned short* base = h2 + (size_t)(f >> 7) * N_NODES * 128 + (f & 127);
    const int n0 = strip * 40, n1 = n0 + 40;
    int g = batch[n0];
    float ax = 0.f, ay = 0.f;
    for (int n = n0; n < n1; ++n) {
        const int bg = batch[n];
        if (bg != g) {
            unsafeAtomicAdd(&pooled[g * NFEAT + f], ax);
            unsafeAtomicAdd(&pooled[g * NFEAT + f + 1], ay);
            ax = ay = 0.f;
            g = bg;
        }
        const unsigned int u = *(const unsigned int*)(base + (size_t)n * 128);
        ax += h2f((unsigned short)(u & 0xffff));
        ay += h2f((unsigned short)(u >> 16));
    }
    unsafeAtomicAdd(&pooled[g * NFEAT + f], ax);
    unsafeAtomicAdd(&pooled[g * NFEAT + f + 1], ay);
}

__global__ void k_final(const float* __restrict__ pooled, const float* __restrict__ Wout,
                        const float* __restrict__ bout, float* __restrict__ out) {
    const int g = blockIdx.x, t = threadIdx.x;
    float v = pooled[g * NFEAT + t] * Wout[t];
#pragma unroll
    for (int off = 32; off > 0; off >>= 1) v += __shfl_down(v, off, 64);
    __shared__ float sred[4];
    if ((t & 63) == 0) sred[t >> 6] = v;
    __syncthreads();
    if (t == 0) out[g] = sred[0] + sred[1] + sred[2] + sred[3] + bout[0];
}

extern "C" void kernel_launch(void* const* d_in, const int* in_sizes, int n_in,
                              void* d_out, int out_size, void* d_ws, size_t ws_size,
                              hipStream_t stream) {
    const float* x     = (const float*)d_in[0];
    const int*   ei    = (const int*)d_in[1];
    const int*   batch = (const int*)d_in[2];
    const float* W1    = (const float*)d_in[3];
    const float* b1    = (const float*)d_in[4];
    const float* W2    = (const float*)d_in[5];
    const float* b2    = (const float*)d_in[6];
    const float* Wout  = (const float*)d_in[7];
    const float* bout  = (const float*)d_in[8];
    float* out = (float*)d_out;

    const int* srcp = ei;
    const int* dstp = ei + NEDGE;

    const size_t NE128 = (size_t)N_NODES * 128;  // elements per half-plane
    unsigned short* hA = (unsigned short*)d_ws;            // [2][N][128] fp16
    unsigned short* hB = hA + 2 * NE128;                   // [2][N][128] fp16
    float* dinv      = (float*)(hB + 2 * NE128);           // 50000
    float* pooled    = dinv + N_NODES;                     // 16384
    int*   cnt       = (int*)(pooled + NGRAPH * NFEAT);    // 50000 (doubles as cursor)
    int*   row_start = cnt + N_NODES;                      // 50001
    int*   bsum      = row_start + N_NODES + 3;            // 256
    unsigned int* csr = (unsigned int*)(bsum + 256);       // 800000
    unsigned short* w1t = (unsigned short*)(csr + NEDGE);  // 65536 each
    unsigned short* w2t = w1t + 65536;

    const int nblk_edges = (NEDGE + 255) / 256;

    // ---- CSR build ----
    hipMemsetAsync(cnt, 0, N_NODES * sizeof(int), stream);
    k_count<<<nblk_edges, 256, 0, stream>>>(dstp, cnt);
    k_scan1<<<NBLK_SCAN, 256, 0, stream>>>(cnt, row_start, bsum);
    k_scan2<<<1, 256, 0, stream>>>(bsum);
    k_scan3<<<NBLK_SCAN, 256, 0, stream>>>(row_start, bsum, cnt, dinv);
    k_place<<<nblk_edges, 256, 0, stream>>>(srcp, dstp, cnt, dinv, csr);

    // ---- weight prep ----
    k_prep_w<<<512, 256, 0, stream>>>(W1, W2, w1t, w2t);

    const dim3 ggrid((N_NODES + 31) / 32, 2);    // 1563 x 2 = 3126 blocks
    const int agg_grid = (2 * N_NODES + 3) / 4;  // 25000

    // ---- layer 1 (x f32 -> fp16 fused into GEMM A-load) ----
    k_gemm_mfma<true><<<ggrid, 256, 0, stream>>>(x, nullptr, w1t, hA, N_NODES);
    k_aggregate<<<agg_grid, 256, 0, stream>>>(hA, row_start, csr, dinv, b1, hB);

    // ---- layer 2 ----
    k_gemm_mfma<false><<<ggrid, 256, 0, stream>>>(nullptr, hB, w2t, hA, N_NODES);
    k_aggregate<<<agg_grid, 256, 0, stream>>>(hA, row_start, csr, dinv, b2, hB);

    // ---- pooling + head ----
    hipMemsetAsync(pooled, 0, NGRAPH * NFEAT * sizeof(float), stream);
    k_pool<<<625, 256, 0, stream>>>(hB, batch, pooled);
    k_final<<<NGRAPH, 256, 0, stream>>>(pooled, Wout, bout, out);
}

// Round 11
// 280.742 us; speedup vs baseline: 1.1804x; 1.1804x over previous
//
#include <hip/hip_runtime.h>
#include <hip/hip_fp16.h>

#define N_NODES 50000
#define NFEAT   256
#define NGRAPH  64
#define NEDGE   800000
#define NBLK_SCAN 196  // ceil(50000/256)
#define NBLK_M  196    // ceil(50000/256) row-strips for GEMM

typedef __attribute__((ext_vector_type(8))) _Float16 half8;
typedef __attribute__((ext_vector_type(2))) _Float16 h2v;
typedef __attribute__((ext_vector_type(4))) float f32x4;

static __device__ __forceinline__ float h2f(unsigned short u) {
    return __half2float(__ushort_as_half(u));
}
static __device__ __forceinline__ unsigned short f2h(float f) {
    return __half_as_ushort(__float2half(f));
}

// ================= CSR build =================
__global__ void k_count(const int* __restrict__ dst, int* __restrict__ cnt) {
    int e = blockIdx.x * 256 + threadIdx.x;
    if (e < NEDGE) atomicAdd(&cnt[dst[e]], 1);
}

__global__ __launch_bounds__(256) void k_scan1(const int* __restrict__ cnt,
                                               int* __restrict__ row_start,
                                               int* __restrict__ bsum) {
    const int t = threadIdx.x, i = blockIdx.x * 256 + t;
    const int lane = t & 63, w = t >> 6;
    const int c = (i < N_NODES) ? cnt[i] : 0;
    int incl = c;
#pragma unroll
    for (int off = 1; off < 64; off <<= 1) {
        int u = __shfl_up(incl, off, 64);
        if (lane >= off) incl += u;
    }
    __shared__ int wtot[4];
    if (lane == 63) wtot[w] = incl;
    __syncthreads();
    int wbase = 0;
#pragma unroll
    for (int k = 0; k < 4; ++k) wbase += (k < w) ? wtot[k] : 0;
    if (i < N_NODES) row_start[i] = wbase + incl - c;
    if (t == 255) bsum[blockIdx.x] = wbase + incl;
}

__global__ __launch_bounds__(256) void k_scan2(int* __restrict__ bsum) {
    const int t = threadIdx.x, lane = t & 63, w = t >> 6;
    const int c = (t < NBLK_SCAN) ? bsum[t] : 0;
    int incl = c;
#pragma unroll
    for (int off = 1; off < 64; off <<= 1) {
        int u = __shfl_up(incl, off, 64);
        if (lane >= off) incl += u;
    }
    __shared__ int wtot[4];
    if (lane == 63) wtot[w] = incl;
    __syncthreads();
    int wbase = 0;
#pragma unroll
    for (int k = 0; k < 4; ++k) wbase += (k < w) ? wtot[k] : 0;
    if (t < NBLK_SCAN) bsum[t] = wbase + incl - c;
}

__global__ void k_scan3(int* __restrict__ row_start, const int* __restrict__ bsum,
                        int* __restrict__ cnt_cursor, float* __restrict__ dinv) {
    const int i = blockIdx.x * 256 + threadIdx.x;
    if (i >= N_NODES) return;
    const int c = cnt_cursor[i];
    const int start = row_start[i] + bsum[blockIdx.x];
    row_start[i] = start;
    cnt_cursor[i] = start;
    dinv[i] = rsqrtf((float)c + 1.0f);
    if (i == 0) row_start[N_NODES] = NEDGE;
}

__global__ void k_place(const int* __restrict__ src, const int* __restrict__ dst,
                        int* __restrict__ cursor, const float* __restrict__ dinv,
                        unsigned int* __restrict__ csr) {
    int e = blockIdx.x * 256 + threadIdx.x;
    if (e < NEDGE) {
        int s = src[e], d = dst[e];
        float norm = dinv[s] * dinv[d];
        int pos = atomicAdd(&cursor[d], 1);
        csr[pos] = ((unsigned int)f2h(norm) << 16) | (unsigned int)s;
    }
}

// ================= W prep: W[k][n] f32 -> Wt [n][k] fp16 =================
__global__ void k_prep_w(const float* __restrict__ W1, const float* __restrict__ W2,
                         unsigned short* __restrict__ w1t, unsigned short* __restrict__ w2t) {
    const int l = blockIdx.x >> 8;
    const int idx = (blockIdx.x & 255) * 256 + threadIdx.x;
    const int n = idx >> 8, k = idx & 255;
    const float* W = l ? W2 : W1;
    unsigned short* wt = l ? w2t : w1t;
    wt[n * 256 + k] = f2h(W[k * 256 + n]);
}

// ================= fp16 MFMA GEMM: C[half][node][128] = A[M,256] @ W =================
// Barrier-free main loop: FULL B-half (256K x 128N = 64KB) staged in LDS once,
// one __syncthreads, then each wave streams 64 A-rows (4 chunks of 16) with
// ping-pong register prefetch. Grid (196, 2); 2 blocks/CU (LDS-capped).
template <bool AF32>
__global__ __launch_bounds__(256) void k_gemm_mfma(const float* __restrict__ Af,
                                                   const unsigned short* __restrict__ Ah,
                                                   const unsigned short* __restrict__ Wt,
                                                   unsigned short* __restrict__ Ch, int M) {
    __shared__ unsigned short lds[32768];  // 64KB: [ks(8)][n(128)][32k] swizzled k-groups
    const int t = threadIdx.x;
    const int half = blockIdx.y;
    const int m0 = blockIdx.x * 256;
    const int w = t >> 6, lane = t & 63;
    const int lr = lane & 15, g = lane >> 4;

    // ---- stage full B-half into LDS (once) ----
    {
        const unsigned short* wbase = Wt + (size_t)half * 128 * 256;
#pragma unroll
        for (int it = 0; it < 16; ++it) {
            const int unit = it * 256 + t;    // 0..4095 16B-units
            const int n = unit >> 5;          // 0..127
            const int rem = unit & 31;        // 32 units per row (512B)
            const int ks = rem >> 2, kg = rem & 3;
            const half8 v = *(const half8*)&wbase[n * 256 + rem * 8];
            const int kgx = kg ^ ((n >> 1) & 3);
            *(half8*)&lds[ks * 4096 + n * 32 + kgx * 8] = v;
        }
    }
    __syncthreads();  // the ONLY barrier

    const int rbase = m0 + w * 64;
    unsigned short* Chh = Ch + (size_t)half * (size_t)N_NODES * 128;

    half8 aA[8], aB[8];

#define LOADCHUNK(C, DST)                                                                \
    {                                                                                    \
        const int row = min(rbase + (C) * 16 + lr, M - 1);                               \
        _Pragma("unroll") for (int ks = 0; ks < 8; ++ks) {                               \
            if (AF32) {                                                                  \
                const float* ap = Af + (size_t)row * 256 + ks * 32 + g * 8;              \
                const float4 p0 = *(const float4*)ap;                                    \
                const float4 p1 = *(const float4*)(ap + 4);                              \
                half8 h;                                                                 \
                h[0] = (_Float16)p0.x; h[1] = (_Float16)p0.y;                            \
                h[2] = (_Float16)p0.z; h[3] = (_Float16)p0.w;                            \
                h[4] = (_Float16)p1.x; h[5] = (_Float16)p1.y;                            \
                h[6] = (_Float16)p1.z; h[7] = (_Float16)p1.w;                            \
                DST[ks] = h;                                                             \
            } else {                                                                     \
                DST[ks] = *(const half8*)(Ah + (size_t)(ks >> 2) * (size_t)N_NODES * 128 \
                                          + (size_t)row * 128 + (ks & 3) * 32 + g * 8);  \
            }                                                                            \
        }                                                                                \
    }

#define COMPUTE(C, SRC)                                                                  \
    {                                                                                    \
        f32x4 acc[8] = {};                                                               \
        _Pragma("unroll") for (int ks = 0; ks < 8; ++ks) {                               \
            _Pragma("unroll") for (int ni = 0; ni < 8; ++ni) {                           \
                const int n = ni * 16 + lr;                                              \
                const half8 bf = *(const half8*)&lds[ks * 4096 + n * 32 +                \
                                                     ((g ^ ((n >> 1) & 3)) << 3)];       \
                acc[ni] = __builtin_amdgcn_mfma_f32_16x16x32_f16(SRC[ks], bf,            \
                                                                 acc[ni], 0, 0, 0);      \
            }                                                                            \
        }                                                                                \
        const int r0 = rbase + (C) * 16 + g * 4;                                         \
        _Pragma("unroll") for (int ni = 0; ni < 8; ++ni) {                               \
            const int col = ni * 16 + lr;                                                \
            _Pragma("unroll") for (int r = 0; r < 4; ++r) {                              \
                if (r0 + r < M) Chh[(size_t)(r0 + r) * 128 + col] = f2h(acc[ni][r]);     \
            }                                                                            \
        }                                                                                \
    }

    LOADCHUNK(0, aA)
    LOADCHUNK(1, aB)
    COMPUTE(0, aA)
    LOADCHUNK(2, aA)
    COMPUTE(1, aB)
    LOADCHUNK(3, aB)
    COMPUTE(2, aA)
    COMPUTE(3, aB)

#undef LOADCHUNK
#undef COMPUTE
}

// ================= aggregation: wave per (node, half); 16 lanes/edge; fdot2 ===========
__global__ __launch_bounds__(256) void k_aggregate(const unsigned short* __restrict__ h16,
                                                   const int* __restrict__ row_start,
                                                   const unsigned int* __restrict__ csr,
                                                   const float* __restrict__ dinv,
                                                   const float* __restrict__ bias,
                                                   unsigned short* __restrict__ out) {
    const int wid = blockIdx.x * 4 + (threadIdx.x >> 6);
    if (wid >= 2 * N_NODES) return;
    const int half = (wid >= N_NODES) ? 1 : 0;  // all half-0 wids first
    const int node = wid - half * N_NODES;
    const int lane = threadIdx.x & 63;
    const int sub = lane >> 4;   // 0..3: edge-pair index
    const int fl = lane & 15;    // 8 feats per lane
    const unsigned int* hu = (const unsigned int*)(h16 + (size_t)half * N_NODES * 128);

    float acc[8] = {};
    const int s0 = row_start[node], s1 = row_start[node + 1];
    const unsigned int* row = csr + s0;
    const int n = s1 - s0;

#define EDGEPAIR(EA, EB)                                                              \
    {                                                                                 \
        const unsigned int wnp = __builtin_amdgcn_perm(EB, EA, 0x07060302u);          \
        const h2v wn2 = __builtin_bit_cast(h2v, wnp);                                 \
        const uint4 va = *(const uint4*)(hu + (size_t)((EA)&0xffffu) * 64 + fl * 4);  \
        const uint4 vb = *(const uint4*)(hu + (size_t)((EB)&0xffffu) * 64 + fl * 4);  \
        unsigned int plo, phi;                                                        \
        plo = __builtin_amdgcn_perm(vb.x, va.x, 0x05040100u);                         \
        phi = __builtin_amdgcn_perm(vb.x, va.x, 0x07060302u);                         \
        acc[0] = __builtin_amdgcn_fdot2(__builtin_bit_cast(h2v, plo), wn2, acc[0], false); \
        acc[1] = __builtin_amdgcn_fdot2(__builtin_bit_cast(h2v, phi), wn2, acc[1], false); \
        plo = __builtin_amdgcn_perm(vb.y, va.y, 0x05040100u);                         \
        phi = __builtin_amdgcn_perm(vb.y, va.y, 0x07060302u);                         \
        acc[2] = __builtin_amdgcn_fdot2(__builtin_bit_cast(h2v, plo), wn2, acc[2], false); \
        acc[3] = __builtin_amdgcn_fdot2(__builtin_bit_cast(h2v, phi), wn2, acc[3], false); \
        plo = __builtin_amdgcn_perm(vb.z, va.z, 0x05040100u);                         \
        phi = __builtin_amdgcn_perm(vb.z, va.z, 0x07060302u);                         \
        acc[4] = __builtin_amdgcn_fdot2(__builtin_bit_cast(h2v, plo), wn2, acc[4], false); \
        acc[5] = __builtin_amdgcn_fdot2(__builtin_bit_cast(h2v, phi), wn2, acc[5], false); \
        plo = __builtin_amdgcn_perm(vb.w, va.w, 0x05040100u);                         \
        phi = __builtin_amdgcn_perm(vb.w, va.w, 0x07060302u);                         \
        acc[6] = __builtin_amdgcn_fdot2(__builtin_bit_cast(h2v, plo), wn2, acc[6], false); \
        acc[7] = __builtin_amdgcn_fdot2(__builtin_bit_cast(h2v, phi), wn2, acc[7], false); \
    }

    const int nfull = n & ~7;
    int j = 0;
    for (; j < nfull; j += 8) {
        const unsigned int ea = row[j + sub * 2];
        const unsigned int eb = row[j + sub * 2 + 1];
        EDGEPAIR(ea, eb)
    }
    if (j < n) {  // guarded tail (invalid slots: e=0 -> wn=0 -> contributes 0)
        const int ia = j + sub * 2, ib = ia + 1;
        const unsigned int ea = (ia < n) ? row[ia] : 0u;
        const unsigned int eb = (ib < n) ? row[ib] : 0u;
        EDGEPAIR(ea, eb)
    }
#undef EDGEPAIR

#pragma unroll
    for (int i = 0; i < 8; ++i) {
        acc[i] += __shfl_xor(acc[i], 16, 64);
        acc[i] += __shfl_xor(acc[i], 32, 64);
    }

    if (sub == 0) {  // lanes 0-15 hold the final sums
        const float dd = dinv[node];
        const float ws = dd * dd;
        const uint4 sh = *(const uint4*)(hu + (size_t)node * 64 + fl * 4);
        const float4 b0 = *(const float4*)(bias + half * 128 + fl * 8);
        const float4 b1 = *(const float4*)(bias + half * 128 + fl * 8 + 4);
        float r[8];
        r[0] = fmaf(h2f((unsigned short)(sh.x & 0xffff)), ws, acc[0]) + b0.x;
        r[1] = fmaf(h2f((unsigned short)(sh.x >> 16)),    ws, acc[1]) + b0.y;
        r[2] = fmaf(h2f((unsigned short)(sh.y & 0xffff)), ws, acc[2]) + b0.z;
        r[3] = fmaf(h2f((unsigned short)(sh.y >> 16)),    ws, acc[3]) + b0.w;
        r[4] = fmaf(h2f((unsigned short)(sh.z & 0xffff)), ws, acc[4]) + b1.x;
        r[5] = fmaf(h2f((unsigned short)(sh.z >> 16)),    ws, acc[5]) + b1.y;
        r[6] = fmaf(h2f((unsigned short)(sh.w & 0xffff)), ws, acc[6]) + b1.z;
        r[7] = fmaf(h2f((unsigned short)(sh.w >> 16)),    ws, acc[7]) + b1.w;
#pragma unroll
        for (int i = 0; i < 8; ++i) r[i] = fmaxf(r[i], 0.f);
        uint4 o;
        o.x = (unsigned int)f2h(r[0]) | ((unsigned int)f2h(r[1]) << 16);
        o.y = (unsigned int)f2h(r[2]) | ((unsigned int)f2h(r[3]) << 16);
        o.z = (unsigned int)f2h(r[4]) | ((unsigned int)f2h(r[5]) << 16);
        o.w = (unsigned int)f2h(r[6]) | ((unsigned int)f2h(r[7]) << 16);
        *(uint4*)((unsigned int*)(out + (size_t)half * N_NODES * 128) +
                  (size_t)node * 64 + fl * 4) = o;
    }
}

// ================= pooling (batch sorted) + head =================
__global__ void k_pool(const unsigned short* __restrict__ h2, const int* __restrict__ batch,
                       float* __restrict__ pooled) {
    const int strip = blockIdx.x * 2 + (threadIdx.x >> 7);
    const int tf = threadIdx.x & 127;
    const int f = tf * 2;
    const unsigned short* base = h2 + (size_t)(f >> 7) * N_NODES * 128 + (f & 127);
    const int n0 = strip * 40, n1 = n0 + 40;
    int g = batch[n0];
    float ax = 0.f, ay = 0.f;
    for (int n = n0; n < n1; ++n) {
        const int bg = batch[n];
        if (bg != g) {
            unsafeAtomicAdd(&pooled[g * NFEAT + f], ax);
            unsafeAtomicAdd(&pooled[g * NFEAT + f + 1], ay);
            ax = ay = 0.f;
            g = bg;
        }
        const unsigned int u = *(const unsigned int*)(base + (size_t)n * 128);
        ax += h2f((unsigned short)(u & 0xffff));
        ay += h2f((unsigned short)(u >> 16));
    }
    unsafeAtomicAdd(&pooled[g * NFEAT + f], ax);
    unsafeAtomicAdd(&pooled[g * NFEAT + f + 1], ay);
}

__global__ void k_final(const float* __restrict__ pooled, const float* __restrict__ Wout,
                        const float* __restrict__ bout, float* __restrict__ out) {
    const int g = blockIdx.x, t = threadIdx.x;
    float v = pooled[g * NFEAT + t] * Wout[t];
#pragma unroll
    for (int off = 32; off > 0; off >>= 1) v += __shfl_down(v, off, 64);
    __shared__ float sred[4];
    if ((t & 63) == 0) sred[t >> 6] = v;
    __syncthreads();
    if (t == 0) out[g] = sred[0] + sred[1] + sred[2] + sred[3] + bout[0];
}

extern "C" void kernel_launch(void* const* d_in, const int* in_sizes, int n_in,
                              void* d_out, int out_size, void* d_ws, size_t ws_size,
                              hipStream_t stream) {
    const float* x     = (const float*)d_in[0];
    const int*   ei    = (const int*)d_in[1];
    const int*   batch = (const int*)d_in[2];
    const float* W1    = (const float*)d_in[3];
    const float* b1    = (const float*)d_in[4];
    const float* W2    = (const float*)d_in[5];
    const float* b2    = (const float*)d_in[6];
    const float* Wout  = (const float*)d_in[7];
    const float* bout  = (const float*)d_in[8];
    float* out = (float*)d_out;

    const int* srcp = ei;
    const int* dstp = ei + NEDGE;

    const size_t NE128 = (size_t)N_NODES * 128;  // elements per half-plane
    unsigned short* hA = (unsigned short*)d_ws;            // [2][N][128] fp16
    unsigned short* hB = hA + 2 * NE128;                   // [2][N][128] fp16
    float* dinv      = (float*)(hB + 2 * NE128);           // 50000
    float* pooled    = dinv + N_NODES;                     // 16384
    int*   cnt       = (int*)(pooled + NGRAPH * NFEAT);    // 50000 (doubles as cursor)
    int*   row_start = cnt + N_NODES;                      // 50001
    int*   bsum      = row_start + N_NODES + 3;            // 256
    unsigned int* csr = (unsigned int*)(bsum + 256);       // 800000
    unsigned short* w1t = (unsigned short*)(csr + NEDGE);  // 65536 each
    unsigned short* w2t = w1t + 65536;

    const int nblk_edges = (NEDGE + 255) / 256;

    // ---- CSR build ----
    hipMemsetAsync(cnt, 0, N_NODES * sizeof(int), stream);
    k_count<<<nblk_edges, 256, 0, stream>>>(dstp, cnt);
    k_scan1<<<NBLK_SCAN, 256, 0, stream>>>(cnt, row_start, bsum);
    k_scan2<<<1, 256, 0, stream>>>(bsum);
    k_scan3<<<NBLK_SCAN, 256, 0, stream>>>(row_start, bsum, cnt, dinv);
    k_place<<<nblk_edges, 256, 0, stream>>>(srcp, dstp, cnt, dinv, csr);

    // ---- weight prep ----
    k_prep_w<<<512, 256, 0, stream>>>(W1, W2, w1t, w2t);

    const dim3 ggrid(NBLK_M, 2);                 // 196 x 2 = 392 blocks, 2/CU
    const int agg_grid = (2 * N_NODES + 3) / 4;  // 25000

    // ---- layer 1 (x f32 -> fp16 fused into GEMM A-load) ----
    k_gemm_mfma<true><<<ggrid, 256, 0, stream>>>(x, nullptr, w1t, hA, N_NODES);
    k_aggregate<<<agg_grid, 256, 0, stream>>>(hA, row_start, csr, dinv, b1, hB);

    // ---- layer 2 ----
    k_gemm_mfma<false><<<ggrid, 256, 0, stream>>>(nullptr, hB, w2t, hA, N_NODES);
    k_aggregate<<<agg_grid, 256, 0, stream>>>(hA, row_start, csr, dinv, b2, hB);

    // ---- pooling + head ----
    hipMemsetAsync(pooled, 0, NGRAPH * NFEAT * sizeof(float), stream);
    k_pool<<<625, 256, 0, stream>>>(hB, batch, pooled);
    k_final<<<NGRAPH, 256, 0, stream>>>(pooled, Wout, bout, out);
}